// Round 13
// baseline (198.410 us; speedup 1.0000x reference)
//
#include <hip/hip_runtime.h>

// UFO linear attention, MI355X (gfx950). B=8, N=4096, C=512, H=8, DK=DV=64.
//
// R16: split the barrier gang. R10/R15 killed the drain/count theories;
// what m97 (490 cyc/K-step) has and every R11-R15 variant lacks is
// MULTIPLE INDEPENDENT BLOCKS per CU overlapping each other's barrier
// stalls. Same R14 core re-dimensioned M64 x N512: 512 thr / 8 waves
// (wave = one 64x64 head strip), LDS A 2x4K + B 2x32K = 72 KB -> 2
// independent blocks/CU (16 waves/CU, occupancy unchanged). B restage
// x2 (L2-resident, LDS-port headroom absorbs it). A still read once.
// kv chain / cast4 / launcher layout = R14 (passed, 173.5 us).

typedef __attribute__((ext_vector_type(4))) float f32x4;
typedef __attribute__((ext_vector_type(8))) short s16x8;
typedef __attribute__((ext_vector_type(4))) unsigned short u16x4;
typedef __attribute__((ext_vector_type(8))) unsigned short u16x8;
typedef __attribute__((ext_vector_type(2))) unsigned u32x2;

#define DEVFN __device__ __forceinline__

DEVFN unsigned short f2b(float f) {  // fp32 -> bf16 RNE
  union { float f; unsigned u; } un; un.f = f;
  unsigned r = un.u + 0x7fffu + ((un.u >> 16) & 1u);
  return (unsigned short)(r >> 16);
}
DEVFN float b2f(unsigned short us) {
  union { unsigned u; float f; } un; un.u = ((unsigned)us) << 16;
  return un.f;
}
// pack two fp32 -> dword of 2 bf16 (round-half-up): 2 adds + 1 v_perm
DEVFN unsigned pk2(float x0, float x1) {
  union { float f; unsigned u; } a, b;
  a.f = x0; b.f = x1;
  return __builtin_amdgcn_perm(b.u + 0x8000u, a.u + 0x8000u, 0x07060302u);
}
// async global->LDS, 16 B per lane; lds dest = wave-uniform base + lane*16
DEVFN void gl_lds16(const void* g, void* l) {
  __builtin_amdgcn_global_load_lds(
      (const __attribute__((address_space(1))) unsigned*)g,
      (__attribute__((address_space(3))) unsigned*)l, 16, 0, 0);
}

// ---------------------------------------------------------------------------
// M-tile 64 x FULL N=512, BK=32, K=512 (16 K-tiles). 512 thr = 8 waves,
// wave w owns cols [w*64, w*64+64) = head w; all waves cover all 64 rows.
// C[m][n] = sum_k A[m][k]*Bt[n][k] + bias[n]; optional fused head-norm.
// ---------------------------------------------------------------------------
template <bool AF32, typename CT>
DEVFN void gemmN512(const void* Ain, const unsigned short* Bt,
                    const float* bias, CT* C, bool qnorm,
                    const float* gamma, int bx) {
  __shared__ __align__(16) char LA[2][4096];   // [buf][64 rows][64 B]
  __shared__ __align__(16) char LB[2][32768];  // [buf][512 rows][64 B]
  const int tid = threadIdx.x, lane = tid & 63, wid = tid >> 6;  // 0..7
  const int r = lane & 15, g = lane >> 4;
  const int nw = wid;  // 0..7 (N eighth = head)

  // B stage: 4 chunks/wave; chunk c = wid*4+q covers rows [c*16, c*16+16);
  // lane l -> row +(l>>2), source slot (l&3)^((l>>3)&3)  [16-row periodic].
  const char* BsS = (const char*)Bt + (long)(wid * 64 + (lane >> 2)) * 1024 +
                    (((lane & 3) ^ ((lane >> 3) & 3)) * 16);

  // A sources
  const char* AfS = nullptr;  // fp32 (proj): thread t -> row t>>3, piece t&7
  const char* AsS = nullptr;  // bf16 (final): waves 0..3 stage 1 chunk each
  int awr = 0;                // swizzled 8-B ds_write offset (proj)
  if constexpr (AF32) {
    AfS = (const char*)Ain + (long)(bx * 64 + (tid >> 3)) * 2048 +
          (tid & 7) * 16;
    const int row = tid >> 3, p = tid & 7;  // row 0..63
    awr = row * 64 + (((p >> 1) ^ ((row >> 1) & 3)) << 4) + (p & 1) * 8;
  } else {
    AsS = (const char*)Ain + (long)(bx * 64 + wid * 16 + (lane >> 2)) * 1024 +
          (((lane & 3) ^ ((lane >> 3) & 3)) * 16);
  }

  f32x4 acc[4][4] = {};
  f32x4 pa;  // proj fp32 A staging (1 per thread)

#define SGB(BUF, KT)                                                           \
  _Pragma("unroll") for (int q = 0; q < 4; ++q)                                \
      gl_lds16(BsS + q * 16384 + (KT)*64, LB[BUF] + (wid * 4 + q) * 1024);
#define SGA(BUF, KT)                                                           \
  if (wid < 4) { gl_lds16(AsS + (KT)*64, LA[BUF] + wid * 1024); }
#define LDA(KT) pa = *reinterpret_cast<const f32x4*>(AfS + (KT)*128);
#define WRA(BUF)                                                               \
  {                                                                            \
    u32x2 w;                                                                   \
    w[0] = pk2(pa[0], pa[1]);                                                  \
    w[1] = pk2(pa[2], pa[3]);                                                  \
    *reinterpret_cast<u32x2*>(LA[BUF] + awr) = w;                              \
  }
#define COMPUTE(BUF)                                                           \
  {                                                                            \
    s16x8 a[4], b[4];                                                          \
    _Pragma("unroll") for (int i = 0; i < 4; ++i) {                            \
      int ar = i * 16 + r;                                                     \
      a[i] = *reinterpret_cast<const s16x8*>(                                  \
          LA[BUF] + ar * 64 + ((g ^ ((ar >> 1) & 3)) << 4));                   \
    }                                                                          \
    _Pragma("unroll") for (int j = 0; j < 4; ++j) {                            \
      int br = nw * 64 + j * 16 + r;                                           \
      b[j] = *reinterpret_cast<const s16x8*>(                                  \
          LB[BUF] + br * 64 + ((g ^ ((br >> 1) & 3)) << 4));                   \
    }                                                                          \
    _Pragma("unroll") for (int i = 0; i < 4; ++i)                              \
        _Pragma("unroll") for (int j = 0; j < 4; ++j) acc[i][j] =              \
        __builtin_amdgcn_mfma_f32_16x16x32_bf16(a[i], b[j], acc[i][j], 0, 0,   \
                                                0);                            \
  }

  // prologue: tile 0 -> buf 0
  if constexpr (AF32) {
    LDA(0) WRA(0)
  } else {
    SGA(0, 0)
  }
  SGB(0, 0)
  __syncthreads();

#pragma unroll 1
  for (int t = 0; t < 15; ++t) {
    const int cur = t & 1, nxt = cur ^ 1;
    if constexpr (AF32) { LDA(t + 1) }  // loads fly under COMPUTE
    SGB(nxt, t + 1)
    if constexpr (!AF32) { SGA(nxt, t + 1) }
    COMPUTE(cur)
    if constexpr (AF32) { WRA(nxt) }  // reg-dep wait lands after compute
    __syncthreads();
  }
  COMPUTE(1)

#undef SGB
#undef SGA
#undef LDA
#undef WRA
#undef COMPUTE

  // ---- epilogue (C/D layout: col=lane&15, row=(lane>>4)*4+ii) ----
  const int crow0 = bx * 64 + g * 4;
  const int ccol0 = nw * 64 + r;
#pragma unroll
  for (int j = 0; j < 4; ++j) {
    float bv = bias[ccol0 + j * 16];
#pragma unroll
    for (int i = 0; i < 4; ++i)
#pragma unroll
      for (int ii = 0; ii < 4; ++ii) acc[i][j][ii] += bv;
  }
  if (qnorm) {  // wave's 64 cols == head nw; L2-norm over them per row
    const float gam = gamma[nw];
#pragma unroll
    for (int i = 0; i < 4; ++i)
#pragma unroll
      for (int ii = 0; ii < 4; ++ii) {
        float s = 0.f;
#pragma unroll
        for (int j = 0; j < 4; ++j) s += acc[i][j][ii] * acc[i][j][ii];
        s += __shfl_xor(s, 1);
        s += __shfl_xor(s, 2);
        s += __shfl_xor(s, 4);
        s += __shfl_xor(s, 8);
        float sc = gam / sqrtf(s);
#pragma unroll
        for (int j = 0; j < 4; ++j) acc[i][j][ii] *= sc;
      }
  }
#pragma unroll
  for (int i = 0; i < 4; ++i)
#pragma unroll
    for (int j = 0; j < 4; ++j)
#pragma unroll
      for (int ii = 0; ii < 4; ++ii) {
        long row = crow0 + i * 16 + ii;
        int col = ccol0 + j * 16;
        if constexpr (sizeof(CT) == 2)
          C[row * 512 + col] = f2b(acc[i][j][ii]);
        else
          C[row * 512 + col] = acc[i][j][ii];
      }
}

__global__ __launch_bounds__(512, 4)
void proj_qkv(const float* __restrict__ Aq, const float* __restrict__ Ak,
              const float* __restrict__ Av, const unsigned short* __restrict__ Bq,
              const unsigned short* __restrict__ Bk, const unsigned short* __restrict__ Bv,
              const float* __restrict__ bq, const float* __restrict__ bk,
              const float* __restrict__ bv, unsigned short* __restrict__ Cq,
              unsigned short* __restrict__ Ck, unsigned short* __restrict__ Cv,
              const float* __restrict__ gamma) {
  const int z = blockIdx.y;
  const float* A = z == 0 ? Aq : (z == 1 ? Ak : Av);
  const unsigned short* B = z == 0 ? Bq : (z == 1 ? Bk : Bv);
  const float* bias = z == 0 ? bq : (z == 1 ? bk : bv);
  unsigned short* C = z == 0 ? Cq : (z == 1 ? Ck : Cv);
  gemmN512<true, unsigned short>(A, B, bias, C, z == 0, gamma, blockIdx.x);
}

__global__ __launch_bounds__(512, 4)
void gemm_final(const unsigned short* __restrict__ q, const unsigned short* __restrict__ Mt,
                const float* __restrict__ bo, float* __restrict__ out) {
  const int zb = blockIdx.y;
  gemmN512<false, float>(q + (long)zb * 2097152, Mt + (long)zb * 262144, bo,
                         out + (long)zb * 2097152, false, nullptr, blockIdx.x);
}

// ---------------------------------------------------------------------------
// kv partials: part[chunk][bh][dk][dv] = sum over 512 n of k outer v
// u16x8 loads (16 B/lane); NCHUNK=8 (part = 8 MB; Mt lives at part+8MB).
// ---------------------------------------------------------------------------
#define NCHUNK 8
__global__ __launch_bounds__(256, 2)
void kv_partial(const unsigned short* __restrict__ kq,
                const unsigned short* __restrict__ vq,
                float* __restrict__ part) {
  const int tid = threadIdx.x;
  const int chunk = blockIdx.x;  // 0..7
  const int bh = blockIdx.y;     // 0..63
  const int b = bh >> 3, h = bh & 7;
  __shared__ float ks[32][64];
  __shared__ float vs[32][64];
  const int dk0 = (tid & 15) * 4;
  const int dv0 = (tid >> 4) * 4;
  float acc[4][4] = {};
  const long nbase = (long)b * 4096 + chunk * 512;
  const int lrow = tid >> 3, lc8 = tid & 7;  // 32 rows x 8 col-groups of 8

  for (int sub = 0; sub < 16; ++sub) {
    long n0 = nbase + sub * 32;
    {
      long gofs = (n0 + lrow) * 512 + h * 64 + lc8 * 8;
      u16x8 kk = *reinterpret_cast<const u16x8*>(kq + gofs);
      u16x8 vv = *reinterpret_cast<const u16x8*>(vq + gofs);
      f32x4 k0 = {b2f(kk[0]), b2f(kk[1]), b2f(kk[2]), b2f(kk[3])};
      f32x4 k1 = {b2f(kk[4]), b2f(kk[5]), b2f(kk[6]), b2f(kk[7])};
      f32x4 v0 = {b2f(vv[0]), b2f(vv[1]), b2f(vv[2]), b2f(vv[3])};
      f32x4 v1 = {b2f(vv[4]), b2f(vv[5]), b2f(vv[6]), b2f(vv[7])};
      *reinterpret_cast<f32x4*>(&ks[lrow][lc8 * 8]) = k0;
      *reinterpret_cast<f32x4*>(&ks[lrow][lc8 * 8 + 4]) = k1;
      *reinterpret_cast<f32x4*>(&vs[lrow][lc8 * 8]) = v0;
      *reinterpret_cast<f32x4*>(&vs[lrow][lc8 * 8 + 4]) = v1;
    }
    __syncthreads();
#pragma unroll 4
    for (int n = 0; n < 32; ++n) {
      f32x4 kk = *reinterpret_cast<const f32x4*>(&ks[n][dk0]);
      f32x4 vv = *reinterpret_cast<const f32x4*>(&vs[n][dv0]);
#pragma unroll
      for (int a = 0; a < 4; ++a)
#pragma unroll
        for (int c = 0; c < 4; ++c)
          acc[a][c] += kk[a] * vv[c];
    }
    __syncthreads();
  }
  float* pg = part + ((long)chunk * 64 + bh) * 4096;
#pragma unroll
  for (int a = 0; a < 4; ++a) {
    f32x4 o = {acc[a][0], acc[a][1], acc[a][2], acc[a][3]};
    *reinterpret_cast<f32x4*>(pg + (dk0 + a) * 64 + dv0) = o;
  }
}

// ---------------------------------------------------------------------------
// Merged: reduce partials + L2-norm (over dv) * gamma -> kvn in padded LDS,
// then Mt[b][c][h*64+dk] = sum_dv Wo[c][h*64+dv] * kvn[dk][dv] (4 waves = 4
// 128-col segs). kvn LDS pitch 72 shorts (144 B).
// ---------------------------------------------------------------------------
__global__ __launch_bounds__(256)
void kv_norm_mt(const float* __restrict__ part, const float* __restrict__ gamma,
                const unsigned short* __restrict__ Wo_b,
                unsigned short* __restrict__ Mt) {
  const int bh = blockIdx.x, h = bh & 7, b = bh >> 3;
  const int tid = threadIdx.x;
  __shared__ float kvs[4096];
  __shared__ float scale_s[64];
  __shared__ __align__(16) unsigned short kvn_l[64 * 72];  // padded

  // phase A: reduce 8 partial chunks
#pragma unroll
  for (int i = 0; i < 4; ++i) {
    int e4 = i * 256 + tid;
    const float* p = part + (long)bh * 4096 + e4 * 4;
    f32x4 s = {0.f, 0.f, 0.f, 0.f};
#pragma unroll
    for (int c = 0; c < NCHUNK; ++c) {
      f32x4 v = *reinterpret_cast<const f32x4*>(p + (long)c * 64 * 4096);
      s += v;
    }
    *reinterpret_cast<f32x4*>(kvs + e4 * 4) = s;
  }
  __syncthreads();
  if (tid < 64) {
    float s = 0.f;
    for (int dv = 0; dv < 64; ++dv) { float x = kvs[tid * 64 + dv]; s += x * x; }
    scale_s[tid] = gamma[h] / sqrtf(s);
  }
  __syncthreads();
#pragma unroll
  for (int i = 0; i < 4; ++i) {
    int e4 = i * 256 + tid;
    int row = e4 >> 4, c0 = (e4 & 15) * 4;
    float sc = scale_s[row];
    f32x4 v = *reinterpret_cast<const f32x4*>(kvs + e4 * 4);
    u16x4 o = {f2b(v[0] * sc), f2b(v[1] * sc), f2b(v[2] * sc), f2b(v[3] * sc)};
    *reinterpret_cast<u16x4*>(kvn_l + row * 72 + c0) = o;
  }
  __syncthreads();

  // phase B: mt for seg = wave id
  const int seg = tid >> 6;
  const int lane = tid & 63;
  const int r = lane & 15, g = lane >> 4;
  f32x4 acc[8][4] = {};
  s16x8 bf[2][4];
#pragma unroll
  for (int ks = 0; ks < 2; ++ks)
#pragma unroll
    for (int j = 0; j < 4; ++j)
      bf[ks][j] = *reinterpret_cast<const s16x8*>(
          kvn_l + (j * 16 + r) * 72 + ks * 32 + g * 8);
#pragma unroll
  for (int ks = 0; ks < 2; ++ks)
#pragma unroll
    for (int i = 0; i < 8; ++i) {
      s16x8 af = *reinterpret_cast<const s16x8*>(
          Wo_b + (long)(seg * 128 + i * 16 + r) * 512 + h * 64 + ks * 32 + g * 8);
#pragma unroll
      for (int j = 0; j < 4; ++j)
        acc[i][j] = __builtin_amdgcn_mfma_f32_16x16x32_bf16(af, bf[ks][j], acc[i][j], 0, 0, 0);
    }
#pragma unroll
  for (int i = 0; i < 8; ++i)
#pragma unroll
    for (int j = 0; j < 4; ++j)
#pragma unroll
      for (int ii = 0; ii < 4; ++ii) {
        int c = seg * 128 + i * 16 + g * 4 + ii;
        int dk = j * 16 + r;
        Mt[(long)b * 262144 + (long)c * 512 + h * 64 + dk] = f2b(acc[i][j][ii]);
      }
}

__global__ void cast4(const float* __restrict__ a0, const float* __restrict__ a1,
                      const float* __restrict__ a2, const float* __restrict__ a3,
                      unsigned short* __restrict__ o0, unsigned short* __restrict__ o1,
                      unsigned short* __restrict__ o2, unsigned short* __restrict__ o3) {
  const int y = blockIdx.y;
  const float* in = y == 0 ? a0 : (y == 1 ? a1 : (y == 2 ? a2 : a3));
  unsigned short* out = y == 0 ? o0 : (y == 1 ? o1 : (y == 2 ? o2 : o3));
  int i = blockIdx.x * 256 + threadIdx.x;
  f32x4 v = reinterpret_cast<const f32x4*>(in)[i];
  reinterpret_cast<u16x4*>(out)[i] = u16x4{f2b(v[0]), f2b(v[1]), f2b(v[2]), f2b(v[3])};
}

// ---------------------------------------------------------------------------
extern "C" void kernel_launch(void* const* d_in, const int* in_sizes, int n_in,
                              void* d_out, int out_size, void* d_ws, size_t ws_size,
                              hipStream_t stream) {
  const float* queries = (const float*)d_in[0];
  const float* keys    = (const float*)d_in[1];
  const float* values  = (const float*)d_in[2];
  const float* Wq = (const float*)d_in[3];
  const float* bq = (const float*)d_in[4];
  const float* Wk = (const float*)d_in[5];
  const float* bk = (const float*)d_in[6];
  const float* Wv = (const float*)d_in[7];
  const float* bv = (const float*)d_in[8];
  const float* Wo = (const float*)d_in[9];
  const float* bo = (const float*)d_in[10];
  const float* gamma = (const float*)d_in[11];

  unsigned short* Wq_b = (unsigned short*)d_ws;            // 512 KB each
  unsigned short* Wk_b = Wq_b + 262144;
  unsigned short* Wv_b = Wk_b + 262144;
  unsigned short* Wo_b = Wv_b + 262144;
  unsigned short* q_b  = Wo_b + 262144;                    // 32 MB (holds q_n)
  unsigned short* kvn  = q_b + 16777216;                   // 512 KB (unused)
  float* part = (float*)(kvn + 262144);                    // 8 MB
  unsigned short* Mt = (unsigned short*)(part + 2097152);  // 4 MB, after part
  unsigned short* k_b = (unsigned short*)d_out;            // d_out scratch
  unsigned short* v_b = k_b + 16777216;
  float* out = (float*)d_out;

  cast4<<<dim3(256, 4), 256, 0, stream>>>(Wq, Wk, Wv, Wo, Wq_b, Wk_b, Wv_b, Wo_b);

  proj_qkv<<<dim3(512, 3), 512, 0, stream>>>(
      queries, keys, values, Wq_b, Wk_b, Wv_b, bq, bk, bv, q_b, k_b, v_b, gamma);

  kv_partial<<<dim3(NCHUNK, 64), 256, 0, stream>>>(k_b, v_b, part);
  kv_norm_mt<<<64, 256, 0, stream>>>(part, gamma, Wo_b, Mt);

  gemm_final<<<dim3(64, 8), 512, 0, stream>>>(q_b, Mt, bo, out);
}

// Round 14
// 167.394 us; speedup vs baseline: 1.1853x; 1.1853x over previous
//
#include <hip/hip_runtime.h>

// UFO linear attention, MI355X (gfx950). B=8, N=4096, C=512, H=8, DK=DV=64.
//
// R17: amortize the sync-epoch overhead. R8-R16 all ran ONE K-tile per
// sync; per-epoch fixed cost (16-wave convergence + drain + ds_read ramp)
// measured ~3900 cyc over the ~1600-cyc work floor. Now: 4-deep LDS
// buffers (A 4x8K + B 4x32K = 160 KB, full pool, 1 block/CU), TWO
// K-tiles computed per epoch (32 MFMAs/wave of back-to-back ILP), stages
// issued 2 tiles ahead, ONE __syncthreads per epoch (8 total). WAR: a
// stage's target buffer was last read one epoch earlier, separated by
// that epoch's sync. launch_bounds(1024,4) pins regs <=128/wave so the
// 16-wave block always fits. Everything else = R14 (passed, 173.5 us).

typedef __attribute__((ext_vector_type(4))) float f32x4;
typedef __attribute__((ext_vector_type(8))) short s16x8;
typedef __attribute__((ext_vector_type(4))) unsigned short u16x4;
typedef __attribute__((ext_vector_type(8))) unsigned short u16x8;
typedef __attribute__((ext_vector_type(2))) unsigned u32x2;

#define DEVFN __device__ __forceinline__

DEVFN unsigned short f2b(float f) {  // fp32 -> bf16 RNE
  union { float f; unsigned u; } un; un.f = f;
  unsigned r = un.u + 0x7fffu + ((un.u >> 16) & 1u);
  return (unsigned short)(r >> 16);
}
DEVFN float b2f(unsigned short us) {
  union { unsigned u; float f; } un; un.u = ((unsigned)us) << 16;
  return un.f;
}
// pack two fp32 -> dword of 2 bf16 (round-half-up): 2 adds + 1 v_perm
DEVFN unsigned pk2(float x0, float x1) {
  union { float f; unsigned u; } a, b;
  a.f = x0; b.f = x1;
  return __builtin_amdgcn_perm(b.u + 0x8000u, a.u + 0x8000u, 0x07060302u);
}
// async global->LDS, 16 B per lane; lds dest = wave-uniform base + lane*16
DEVFN void gl_lds16(const void* g, void* l) {
  __builtin_amdgcn_global_load_lds(
      (const __attribute__((address_space(1))) unsigned*)g,
      (__attribute__((address_space(3))) unsigned*)l, 16, 0, 0);
}

// ---------------------------------------------------------------------------
// M-tile 128 x FULL N=512, BK=32, K=512 (16 K-tiles, 8 epochs of 2).
// 1024 thr = 16 waves, wave-tile 64x64 (mw = wid>>3, nw = wid&7 = head).
// C[m][n] = sum_k A[m][k]*Bt[n][k] + bias[n]; optional fused head-norm.
// ---------------------------------------------------------------------------
template <bool AF32, typename CT>
DEVFN void gemmN512(const void* Ain, const unsigned short* Bt,
                    const float* bias, CT* C, bool qnorm,
                    const float* gamma, int bx) {
  __shared__ __align__(16) char LA[4][8192];   // [buf][128 rows][64 B]
  __shared__ __align__(16) char LB[4][32768];  // [buf][512 rows][64 B]
  const int tid = threadIdx.x, lane = tid & 63, wid = tid >> 6;  // 0..15
  const int r = lane & 15, g = lane >> 4;
  const int mw = wid >> 3;  // 0..1  (M half)
  const int nw = wid & 7;   // 0..7  (N eighth = head)

  // B stage: 2 chunks/wave; chunk covers 16 rows; lane l -> row +(l>>2),
  // content-slot (l&3) from pre-swizzled source slot (l&3)^((l>>3)&3).
  const char* BsS = (const char*)Bt + (long)(wid * 32 + (lane >> 2)) * 1024 +
                    (((lane & 3) ^ ((lane >> 3) & 3)) * 16);

  // A sources
  const char* AfS = nullptr;  // fp32 (proj): thread t -> row t>>3, piece t&7
  const char* AsS = nullptr;  // bf16 (final): waves 0..7 stage 1 chunk each
  int awr = 0;                // swizzled 8-B ds_write offset (proj)
  if constexpr (AF32) {
    AfS = (const char*)Ain + (long)(bx * 128 + (tid >> 3)) * 2048 +
          (tid & 7) * 16;
    const int row = tid >> 3, p = tid & 7;
    awr = row * 64 + (((p >> 1) ^ ((row >> 1) & 3)) << 4) + (p & 1) * 8;
  } else {
    AsS = (const char*)Ain + (long)(bx * 128 + wid * 16 + (lane >> 2)) * 1024 +
          (((lane & 3) ^ ((lane >> 3) & 3)) * 16);
  }

  f32x4 acc[4][4] = {};
  f32x4 paA, paB;  // 2-deep fp32 A prefetch (proj)

#define SGB(BUF, KT)                                                           \
  gl_lds16(BsS + (KT)*64, LB[BUF] + wid * 2048);                               \
  gl_lds16(BsS + 16384 + (KT)*64, LB[BUF] + wid * 2048 + 1024);
#define SGA(BUF, KT)                                                           \
  if (wid < 8) { gl_lds16(AsS + (KT)*64, LA[BUF] + wid * 1024); }
#define LDA(P, KT) P = *reinterpret_cast<const f32x4*>(AfS + (KT)*128);
#define WRA(P, BUF)                                                            \
  {                                                                            \
    u32x2 w;                                                                   \
    w[0] = pk2(P[0], P[1]);                                                    \
    w[1] = pk2(P[2], P[3]);                                                    \
    *reinterpret_cast<u32x2*>(LA[BUF] + awr) = w;                              \
  }
#define COMPUTE(BUF)                                                           \
  {                                                                            \
    s16x8 a[4], b[4];                                                          \
    _Pragma("unroll") for (int i = 0; i < 4; ++i) {                            \
      int ar = mw * 64 + i * 16 + r;                                           \
      a[i] = *reinterpret_cast<const s16x8*>(                                  \
          LA[BUF] + ar * 64 + ((g ^ ((ar >> 1) & 3)) << 4));                   \
    }                                                                          \
    _Pragma("unroll") for (int j = 0; j < 4; ++j) {                            \
      int br = nw * 64 + j * 16 + r;                                           \
      b[j] = *reinterpret_cast<const s16x8*>(                                  \
          LB[BUF] + br * 64 + ((g ^ ((br >> 1) & 3)) << 4));                   \
    }                                                                          \
    _Pragma("unroll") for (int i = 0; i < 4; ++i)                              \
        _Pragma("unroll") for (int j = 0; j < 4; ++j) acc[i][j] =              \
        __builtin_amdgcn_mfma_f32_16x16x32_bf16(a[i], b[j], acc[i][j], 0, 0,   \
                                                0);                            \
  }

  // prologue: tiles 0,1 -> bufs 0,1
  if constexpr (AF32) {
    LDA(paA, 0) WRA(paA, 0)   // reg-dep wait; prologue-only cost
    LDA(paB, 1) WRA(paB, 1)
  } else {
    SGA(0, 0) SGA(1, 1)
  }
  SGB(0, 0) SGB(1, 1)
  __syncthreads();

  // 7 staging epochs: epoch at t0 computes t0,t0+1; stages t0+2,t0+3.
#pragma unroll 1
  for (int t0 = 0; t0 < 14; t0 += 2) {
    const int b2 = (t0 + 2) & 3, b3 = (t0 + 3) & 3;
    if constexpr (AF32) {
      LDA(paA, t0 + 2) LDA(paB, t0 + 3)   // loads fly under the 2 COMPUTEs
    }
    SGB(b2, t0 + 2) SGB(b3, t0 + 3)
    if constexpr (!AF32) { SGA(b2, t0 + 2) SGA(b3, t0 + 3) }
    COMPUTE(t0 & 3)
    COMPUTE((t0 + 1) & 3)
    if constexpr (AF32) { WRA(paA, b2) WRA(paB, b3) }
    __syncthreads();
  }
  // final epoch: tiles 14,15 (bufs 2,3)
  COMPUTE(2)
  COMPUTE(3)

#undef SGB
#undef SGA
#undef LDA
#undef WRA
#undef COMPUTE

  // ---- epilogue (C/D layout: col=lane&15, row=(lane>>4)*4+ii) ----
  const int crow0 = bx * 128 + mw * 64 + g * 4;
  const int ccol0 = nw * 64 + r;
#pragma unroll
  for (int j = 0; j < 4; ++j) {
    float bv = bias[ccol0 + j * 16];
#pragma unroll
    for (int i = 0; i < 4; ++i)
#pragma unroll
      for (int ii = 0; ii < 4; ++ii) acc[i][j][ii] += bv;
  }
  if (qnorm) {  // wave's 64 cols == head nw; L2-norm over them per row
    const float gam = gamma[nw];
#pragma unroll
    for (int i = 0; i < 4; ++i)
#pragma unroll
      for (int ii = 0; ii < 4; ++ii) {
        float s = 0.f;
#pragma unroll
        for (int j = 0; j < 4; ++j) s += acc[i][j][ii] * acc[i][j][ii];
        s += __shfl_xor(s, 1);
        s += __shfl_xor(s, 2);
        s += __shfl_xor(s, 4);
        s += __shfl_xor(s, 8);
        float sc = gam / sqrtf(s);
#pragma unroll
        for (int j = 0; j < 4; ++j) acc[i][j][ii] *= sc;
      }
  }
#pragma unroll
  for (int i = 0; i < 4; ++i)
#pragma unroll
    for (int j = 0; j < 4; ++j)
#pragma unroll
      for (int ii = 0; ii < 4; ++ii) {
        long row = crow0 + i * 16 + ii;
        int col = ccol0 + j * 16;
        if constexpr (sizeof(CT) == 2)
          C[row * 512 + col] = f2b(acc[i][j][ii]);
        else
          C[row * 512 + col] = acc[i][j][ii];
      }
}

__global__ __launch_bounds__(1024, 4)
void proj_qkv(const float* __restrict__ Aq, const float* __restrict__ Ak,
              const float* __restrict__ Av, const unsigned short* __restrict__ Bq,
              const unsigned short* __restrict__ Bk, const unsigned short* __restrict__ Bv,
              const float* __restrict__ bq, const float* __restrict__ bk,
              const float* __restrict__ bv, unsigned short* __restrict__ Cq,
              unsigned short* __restrict__ Ck, unsigned short* __restrict__ Cv,
              const float* __restrict__ gamma) {
  const int z = blockIdx.y;
  const float* A = z == 0 ? Aq : (z == 1 ? Ak : Av);
  const unsigned short* B = z == 0 ? Bq : (z == 1 ? Bk : Bv);
  const float* bias = z == 0 ? bq : (z == 1 ? bk : bv);
  unsigned short* C = z == 0 ? Cq : (z == 1 ? Ck : Cv);
  gemmN512<true, unsigned short>(A, B, bias, C, z == 0, gamma, blockIdx.x);
}

__global__ __launch_bounds__(1024, 4)
void gemm_final(const unsigned short* __restrict__ q, const unsigned short* __restrict__ Mt,
                const float* __restrict__ bo, float* __restrict__ out) {
  const int zb = blockIdx.y;
  gemmN512<false, float>(q + (long)zb * 2097152, Mt + (long)zb * 262144, bo,
                         out + (long)zb * 2097152, false, nullptr, blockIdx.x);
}

// ---------------------------------------------------------------------------
// kv partials: part[chunk][bh][dk][dv] = sum over 512 n of k outer v
// u16x8 loads (16 B/lane); NCHUNK=8 (part = 8 MB; Mt lives at part+8MB).
// ---------------------------------------------------------------------------
#define NCHUNK 8
__global__ __launch_bounds__(256, 2)
void kv_partial(const unsigned short* __restrict__ kq,
                const unsigned short* __restrict__ vq,
                float* __restrict__ part) {
  const int tid = threadIdx.x;
  const int chunk = blockIdx.x;  // 0..7
  const int bh = blockIdx.y;     // 0..63
  const int b = bh >> 3, h = bh & 7;
  __shared__ float ks[32][64];
  __shared__ float vs[32][64];
  const int dk0 = (tid & 15) * 4;
  const int dv0 = (tid >> 4) * 4;
  float acc[4][4] = {};
  const long nbase = (long)b * 4096 + chunk * 512;
  const int lrow = tid >> 3, lc8 = tid & 7;  // 32 rows x 8 col-groups of 8

  for (int sub = 0; sub < 16; ++sub) {
    long n0 = nbase + sub * 32;
    {
      long gofs = (n0 + lrow) * 512 + h * 64 + lc8 * 8;
      u16x8 kk = *reinterpret_cast<const u16x8*>(kq + gofs);
      u16x8 vv = *reinterpret_cast<const u16x8*>(vq + gofs);
      f32x4 k0 = {b2f(kk[0]), b2f(kk[1]), b2f(kk[2]), b2f(kk[3])};
      f32x4 k1 = {b2f(kk[4]), b2f(kk[5]), b2f(kk[6]), b2f(kk[7])};
      f32x4 v0 = {b2f(vv[0]), b2f(vv[1]), b2f(vv[2]), b2f(vv[3])};
      f32x4 v1 = {b2f(vv[4]), b2f(vv[5]), b2f(vv[6]), b2f(vv[7])};
      *reinterpret_cast<f32x4*>(&ks[lrow][lc8 * 8]) = k0;
      *reinterpret_cast<f32x4*>(&ks[lrow][lc8 * 8 + 4]) = k1;
      *reinterpret_cast<f32x4*>(&vs[lrow][lc8 * 8]) = v0;
      *reinterpret_cast<f32x4*>(&vs[lrow][lc8 * 8 + 4]) = v1;
    }
    __syncthreads();
#pragma unroll 4
    for (int n = 0; n < 32; ++n) {
      f32x4 kk = *reinterpret_cast<const f32x4*>(&ks[n][dk0]);
      f32x4 vv = *reinterpret_cast<const f32x4*>(&vs[n][dv0]);
#pragma unroll
      for (int a = 0; a < 4; ++a)
#pragma unroll
        for (int c = 0; c < 4; ++c)
          acc[a][c] += kk[a] * vv[c];
    }
    __syncthreads();
  }
  float* pg = part + ((long)chunk * 64 + bh) * 4096;
#pragma unroll
  for (int a = 0; a < 4; ++a) {
    f32x4 o = {acc[a][0], acc[a][1], acc[a][2], acc[a][3]};
    *reinterpret_cast<f32x4*>(pg + (dk0 + a) * 64 + dv0) = o;
  }
}

// ---------------------------------------------------------------------------
// Merged: reduce partials + L2-norm (over dv) * gamma -> kvn in padded LDS,
// then Mt[b][c][h*64+dk] = sum_dv Wo[c][h*64+dv] * kvn[dk][dv] (4 waves = 4
// 128-col segs). kvn LDS pitch 72 shorts (144 B).
// ---------------------------------------------------------------------------
__global__ __launch_bounds__(256)
void kv_norm_mt(const float* __restrict__ part, const float* __restrict__ gamma,
                const unsigned short* __restrict__ Wo_b,
                unsigned short* __restrict__ Mt) {
  const int bh = blockIdx.x, h = bh & 7, b = bh >> 3;
  const int tid = threadIdx.x;
  __shared__ float kvs[4096];
  __shared__ float scale_s[64];
  __shared__ __align__(16) unsigned short kvn_l[64 * 72];  // padded

  // phase A: reduce 8 partial chunks
#pragma unroll
  for (int i = 0; i < 4; ++i) {
    int e4 = i * 256 + tid;
    const float* p = part + (long)bh * 4096 + e4 * 4;
    f32x4 s = {0.f, 0.f, 0.f, 0.f};
#pragma unroll
    for (int c = 0; c < NCHUNK; ++c) {
      f32x4 v = *reinterpret_cast<const f32x4*>(p + (long)c * 64 * 4096);
      s += v;
    }
    *reinterpret_cast<f32x4*>(kvs + e4 * 4) = s;
  }
  __syncthreads();
  if (tid < 64) {
    float s = 0.f;
    for (int dv = 0; dv < 64; ++dv) { float x = kvs[tid * 64 + dv]; s += x * x; }
    scale_s[tid] = gamma[h] / sqrtf(s);
  }
  __syncthreads();
#pragma unroll
  for (int i = 0; i < 4; ++i) {
    int e4 = i * 256 + tid;
    int row = e4 >> 4, c0 = (e4 & 15) * 4;
    float sc = scale_s[row];
    f32x4 v = *reinterpret_cast<const f32x4*>(kvs + e4 * 4);
    u16x4 o = {f2b(v[0] * sc), f2b(v[1] * sc), f2b(v[2] * sc), f2b(v[3] * sc)};
    *reinterpret_cast<u16x4*>(kvn_l + row * 72 + c0) = o;
  }
  __syncthreads();

  // phase B: mt for seg = wave id
  const int seg = tid >> 6;
  const int lane = tid & 63;
  const int r = lane & 15, g = lane >> 4;
  f32x4 acc[8][4] = {};
  s16x8 bf[2][4];
#pragma unroll
  for (int ks = 0; ks < 2; ++ks)
#pragma unroll
    for (int j = 0; j < 4; ++j)
      bf[ks][j] = *reinterpret_cast<const s16x8*>(
          kvn_l + (j * 16 + r) * 72 + ks * 32 + g * 8);
#pragma unroll
  for (int ks = 0; ks < 2; ++ks)
#pragma unroll
    for (int i = 0; i < 8; ++i) {
      s16x8 af = *reinterpret_cast<const s16x8*>(
          Wo_b + (long)(seg * 128 + i * 16 + r) * 512 + h * 64 + ks * 32 + g * 8);
#pragma unroll
      for (int j = 0; j < 4; ++j)
        acc[i][j] = __builtin_amdgcn_mfma_f32_16x16x32_bf16(af, bf[ks][j], acc[i][j], 0, 0, 0);
    }
#pragma unroll
  for (int i = 0; i < 8; ++i)
#pragma unroll
    for (int j = 0; j < 4; ++j)
#pragma unroll
      for (int ii = 0; ii < 4; ++ii) {
        int c = seg * 128 + i * 16 + g * 4 + ii;
        int dk = j * 16 + r;
        Mt[(long)b * 262144 + (long)c * 512 + h * 64 + dk] = f2b(acc[i][j][ii]);
      }
}

__global__ void cast4(const float* __restrict__ a0, const float* __restrict__ a1,
                      const float* __restrict__ a2, const float* __restrict__ a3,
                      unsigned short* __restrict__ o0, unsigned short* __restrict__ o1,
                      unsigned short* __restrict__ o2, unsigned short* __restrict__ o3) {
  const int y = blockIdx.y;
  const float* in = y == 0 ? a0 : (y == 1 ? a1 : (y == 2 ? a2 : a3));
  unsigned short* out = y == 0 ? o0 : (y == 1 ? o1 : (y == 2 ? o2 : o3));
  int i = blockIdx.x * 256 + threadIdx.x;
  f32x4 v = reinterpret_cast<const f32x4*>(in)[i];
  reinterpret_cast<u16x4*>(out)[i] = u16x4{f2b(v[0]), f2b(v[1]), f2b(v[2]), f2b(v[3])};
}

// ---------------------------------------------------------------------------
extern "C" void kernel_launch(void* const* d_in, const int* in_sizes, int n_in,
                              void* d_out, int out_size, void* d_ws, size_t ws_size,
                              hipStream_t stream) {
  const float* queries = (const float*)d_in[0];
  const float* keys    = (const float*)d_in[1];
  const float* values  = (const float*)d_in[2];
  const float* Wq = (const float*)d_in[3];
  const float* bq = (const float*)d_in[4];
  const float* Wk = (const float*)d_in[5];
  const float* bk = (const float*)d_in[6];
  const float* Wv = (const float*)d_in[7];
  const float* bv = (const float*)d_in[8];
  const float* Wo = (const float*)d_in[9];
  const float* bo = (const float*)d_in[10];
  const float* gamma = (const float*)d_in[11];

  unsigned short* Wq_b = (unsigned short*)d_ws;            // 512 KB each
  unsigned short* Wk_b = Wq_b + 262144;
  unsigned short* Wv_b = Wk_b + 262144;
  unsigned short* Wo_b = Wv_b + 262144;
  unsigned short* q_b  = Wo_b + 262144;                    // 32 MB (holds q_n)
  unsigned short* kvn  = q_b + 16777216;                   // 512 KB (unused)
  float* part = (float*)(kvn + 262144);                    // 8 MB
  unsigned short* Mt = (unsigned short*)(part + 2097152);  // 4 MB, after part
  unsigned short* k_b = (unsigned short*)d_out;            // d_out scratch
  unsigned short* v_b = k_b + 16777216;
  float* out = (float*)d_out;

  cast4<<<dim3(256, 4), 256, 0, stream>>>(Wq, Wk, Wv, Wo, Wq_b, Wk_b, Wv_b, Wo_b);

  proj_qkv<<<dim3(256, 3), 1024, 0, stream>>>(
      queries, keys, values, Wq_b, Wk_b, Wv_b, bq, bk, bv, q_b, k_b, v_b, gamma);

  kv_partial<<<dim3(NCHUNK, 64), 256, 0, stream>>>(k_b, v_b, part);
  kv_norm_mt<<<64, 256, 0, stream>>>(part, gamma, Wo_b, Mt);

  gemm_final<<<dim3(32, 8), 1024, 0, stream>>>(q_b, Mt, bo, out);
}

// Round 15
// 166.858 us; speedup vs baseline: 1.1891x; 1.0032x over previous
//
#include <hip/hip_runtime.h>

// UFO linear attention, MI355X (gfx950). B=8, N=4096, C=512, H=8, DK=DV=64.
//
// R18: kv_partial rewritten with 8x8 register blocking + direct global
// loads (no LDS staging). Old version: 4x4 blocking = 1 LDS-B/FLOP ->
// 2.1 GB LDS reads (~27 us, LDS-read-bound). New: one wave covers the
// full 64x64 tile (acc[8][8] = 64 VGPR); per n, two u16x8 global loads
// (L2-resident, coalescer-broadcast) feed 64 FMA; 4 waves per block own
// 128-seq subranges, merged by 3 sequential LDS-add passes at the end.
// FMA floor 13.6 us + cvt ~= 17 us. proj/gemm_final/kv_norm_mt/cast4 =
// R17 verbatim (passed, 167.4 us).

typedef __attribute__((ext_vector_type(4))) float f32x4;
typedef __attribute__((ext_vector_type(8))) short s16x8;
typedef __attribute__((ext_vector_type(4))) unsigned short u16x4;
typedef __attribute__((ext_vector_type(8))) unsigned short u16x8;
typedef __attribute__((ext_vector_type(2))) unsigned u32x2;

#define DEVFN __device__ __forceinline__

DEVFN unsigned short f2b(float f) {  // fp32 -> bf16 RNE
  union { float f; unsigned u; } un; un.f = f;
  unsigned r = un.u + 0x7fffu + ((un.u >> 16) & 1u);
  return (unsigned short)(r >> 16);
}
DEVFN float b2f(unsigned short us) {
  union { unsigned u; float f; } un; un.u = ((unsigned)us) << 16;
  return un.f;
}
// pack two fp32 -> dword of 2 bf16 (round-half-up): 2 adds + 1 v_perm
DEVFN unsigned pk2(float x0, float x1) {
  union { float f; unsigned u; } a, b;
  a.f = x0; b.f = x1;
  return __builtin_amdgcn_perm(b.u + 0x8000u, a.u + 0x8000u, 0x07060302u);
}
// async global->LDS, 16 B per lane; lds dest = wave-uniform base + lane*16
DEVFN void gl_lds16(const void* g, void* l) {
  __builtin_amdgcn_global_load_lds(
      (const __attribute__((address_space(1))) unsigned*)g,
      (__attribute__((address_space(3))) unsigned*)l, 16, 0, 0);
}

// ---------------------------------------------------------------------------
// M-tile 128 x FULL N=512, BK=32, K=512 (16 K-tiles, 8 epochs of 2).
// 1024 thr = 16 waves, wave-tile 64x64 (mw = wid>>3, nw = wid&7 = head).
// C[m][n] = sum_k A[m][k]*Bt[n][k] + bias[n]; optional fused head-norm.
// [R17 core, verbatim]
// ---------------------------------------------------------------------------
template <bool AF32, typename CT>
DEVFN void gemmN512(const void* Ain, const unsigned short* Bt,
                    const float* bias, CT* C, bool qnorm,
                    const float* gamma, int bx) {
  __shared__ __align__(16) char LA[4][8192];   // [buf][128 rows][64 B]
  __shared__ __align__(16) char LB[4][32768];  // [buf][512 rows][64 B]
  const int tid = threadIdx.x, lane = tid & 63, wid = tid >> 6;  // 0..15
  const int r = lane & 15, g = lane >> 4;
  const int mw = wid >> 3;  // 0..1  (M half)
  const int nw = wid & 7;   // 0..7  (N eighth = head)

  // B stage: 2 chunks/wave; chunk covers 16 rows; lane l -> row +(l>>2),
  // content-slot (l&3) from pre-swizzled source slot (l&3)^((l>>3)&3).
  const char* BsS = (const char*)Bt + (long)(wid * 32 + (lane >> 2)) * 1024 +
                    (((lane & 3) ^ ((lane >> 3) & 3)) * 16);

  // A sources
  const char* AfS = nullptr;  // fp32 (proj): thread t -> row t>>3, piece t&7
  const char* AsS = nullptr;  // bf16 (final): waves 0..7 stage 1 chunk each
  int awr = 0;                // swizzled 8-B ds_write offset (proj)
  if constexpr (AF32) {
    AfS = (const char*)Ain + (long)(bx * 128 + (tid >> 3)) * 2048 +
          (tid & 7) * 16;
    const int row = tid >> 3, p = tid & 7;
    awr = row * 64 + (((p >> 1) ^ ((row >> 1) & 3)) << 4) + (p & 1) * 8;
  } else {
    AsS = (const char*)Ain + (long)(bx * 128 + wid * 16 + (lane >> 2)) * 1024 +
          (((lane & 3) ^ ((lane >> 3) & 3)) * 16);
  }

  f32x4 acc[4][4] = {};
  f32x4 paA, paB;  // 2-deep fp32 A prefetch (proj)

#define SGB(BUF, KT)                                                           \
  gl_lds16(BsS + (KT)*64, LB[BUF] + wid * 2048);                               \
  gl_lds16(BsS + 16384 + (KT)*64, LB[BUF] + wid * 2048 + 1024);
#define SGA(BUF, KT)                                                           \
  if (wid < 8) { gl_lds16(AsS + (KT)*64, LA[BUF] + wid * 1024); }
#define LDA(P, KT) P = *reinterpret_cast<const f32x4*>(AfS + (KT)*128);
#define WRA(P, BUF)                                                            \
  {                                                                            \
    u32x2 w;                                                                   \
    w[0] = pk2(P[0], P[1]);                                                    \
    w[1] = pk2(P[2], P[3]);                                                    \
    *reinterpret_cast<u32x2*>(LA[BUF] + awr) = w;                              \
  }
#define COMPUTE(BUF)                                                           \
  {                                                                            \
    s16x8 a[4], b[4];                                                          \
    _Pragma("unroll") for (int i = 0; i < 4; ++i) {                            \
      int ar = mw * 64 + i * 16 + r;                                           \
      a[i] = *reinterpret_cast<const s16x8*>(                                  \
          LA[BUF] + ar * 64 + ((g ^ ((ar >> 1) & 3)) << 4));                   \
    }                                                                          \
    _Pragma("unroll") for (int j = 0; j < 4; ++j) {                            \
      int br = nw * 64 + j * 16 + r;                                           \
      b[j] = *reinterpret_cast<const s16x8*>(                                  \
          LB[BUF] + br * 64 + ((g ^ ((br >> 1) & 3)) << 4));                   \
    }                                                                          \
    _Pragma("unroll") for (int i = 0; i < 4; ++i)                              \
        _Pragma("unroll") for (int j = 0; j < 4; ++j) acc[i][j] =              \
        __builtin_amdgcn_mfma_f32_16x16x32_bf16(a[i], b[j], acc[i][j], 0, 0,   \
                                                0);                            \
  }

  // prologue: tiles 0,1 -> bufs 0,1
  if constexpr (AF32) {
    LDA(paA, 0) WRA(paA, 0)   // reg-dep wait; prologue-only cost
    LDA(paB, 1) WRA(paB, 1)
  } else {
    SGA(0, 0) SGA(1, 1)
  }
  SGB(0, 0) SGB(1, 1)
  __syncthreads();

  // 7 staging epochs: epoch at t0 computes t0,t0+1; stages t0+2,t0+3.
#pragma unroll 1
  for (int t0 = 0; t0 < 14; t0 += 2) {
    const int b2 = (t0 + 2) & 3, b3 = (t0 + 3) & 3;
    if constexpr (AF32) {
      LDA(paA, t0 + 2) LDA(paB, t0 + 3)   // loads fly under the 2 COMPUTEs
    }
    SGB(b2, t0 + 2) SGB(b3, t0 + 3)
    if constexpr (!AF32) { SGA(b2, t0 + 2) SGA(b3, t0 + 3) }
    COMPUTE(t0 & 3)
    COMPUTE((t0 + 1) & 3)
    if constexpr (AF32) { WRA(paA, b2) WRA(paB, b3) }
    __syncthreads();
  }
  // final epoch: tiles 14,15 (bufs 2,3)
  COMPUTE(2)
  COMPUTE(3)

#undef SGB
#undef SGA
#undef LDA
#undef WRA
#undef COMPUTE

  // ---- epilogue (C/D layout: col=lane&15, row=(lane>>4)*4+ii) ----
  const int crow0 = bx * 128 + mw * 64 + g * 4;
  const int ccol0 = nw * 64 + r;
#pragma unroll
  for (int j = 0; j < 4; ++j) {
    float bv = bias[ccol0 + j * 16];
#pragma unroll
    for (int i = 0; i < 4; ++i)
#pragma unroll
      for (int ii = 0; ii < 4; ++ii) acc[i][j][ii] += bv;
  }
  if (qnorm) {  // wave's 64 cols == head nw; L2-norm over them per row
    const float gam = gamma[nw];
#pragma unroll
    for (int i = 0; i < 4; ++i)
#pragma unroll
      for (int ii = 0; ii < 4; ++ii) {
        float s = 0.f;
#pragma unroll
        for (int j = 0; j < 4; ++j) s += acc[i][j][ii] * acc[i][j][ii];
        s += __shfl_xor(s, 1);
        s += __shfl_xor(s, 2);
        s += __shfl_xor(s, 4);
        s += __shfl_xor(s, 8);
        float sc = gam / sqrtf(s);
#pragma unroll
        for (int j = 0; j < 4; ++j) acc[i][j][ii] *= sc;
      }
  }
#pragma unroll
  for (int i = 0; i < 4; ++i)
#pragma unroll
    for (int j = 0; j < 4; ++j)
#pragma unroll
      for (int ii = 0; ii < 4; ++ii) {
        long row = crow0 + i * 16 + ii;
        int col = ccol0 + j * 16;
        if constexpr (sizeof(CT) == 2)
          C[row * 512 + col] = f2b(acc[i][j][ii]);
        else
          C[row * 512 + col] = acc[i][j][ii];
      }
}

__global__ __launch_bounds__(1024, 4)
void proj_qkv(const float* __restrict__ Aq, const float* __restrict__ Ak,
              const float* __restrict__ Av, const unsigned short* __restrict__ Bq,
              const unsigned short* __restrict__ Bk, const unsigned short* __restrict__ Bv,
              const float* __restrict__ bq, const float* __restrict__ bk,
              const float* __restrict__ bv, unsigned short* __restrict__ Cq,
              unsigned short* __restrict__ Ck, unsigned short* __restrict__ Cv,
              const float* __restrict__ gamma) {
  const int z = blockIdx.y;
  const float* A = z == 0 ? Aq : (z == 1 ? Ak : Av);
  const unsigned short* B = z == 0 ? Bq : (z == 1 ? Bk : Bv);
  const float* bias = z == 0 ? bq : (z == 1 ? bk : bv);
  unsigned short* C = z == 0 ? Cq : (z == 1 ? Ck : Cv);
  gemmN512<true, unsigned short>(A, B, bias, C, z == 0, gamma, blockIdx.x);
}

__global__ __launch_bounds__(1024, 4)
void gemm_final(const unsigned short* __restrict__ q, const unsigned short* __restrict__ Mt,
                const float* __restrict__ bo, float* __restrict__ out) {
  const int zb = blockIdx.y;
  gemmN512<false, float>(q + (long)zb * 2097152, Mt + (long)zb * 262144, bo,
                         out + (long)zb * 2097152, false, nullptr, blockIdx.x);
}

// ---------------------------------------------------------------------------
// kv partials: part[chunk][bh][dk][dv] = sum over 512 n of k outer v.
// 8x8 register blocking per lane; direct global u16x8 loads (L2-resident,
// coalescer-broadcast); 4 waves = 4 seq-subranges of 128; merged by 3
// sequential LDS-add passes. No staging LDS in the hot loop.
// ---------------------------------------------------------------------------
#define NCHUNK 8
__global__ __launch_bounds__(256, 2)
void kv_partial(const unsigned short* __restrict__ kq,
                const unsigned short* __restrict__ vq,
                float* __restrict__ part) {
  const int tid = threadIdx.x, lane = tid & 63, wid = tid >> 6;  // 0..3
  const int chunk = blockIdx.x;  // 0..7
  const int bh = blockIdx.y;     // 0..63
  const int b = bh >> 3, h = bh & 7;
  const int dk0 = (lane & 7) * 8;   // 8 dk rows per lane
  const int dv0 = (lane >> 3) * 8;  // 8 dv cols per lane
  __shared__ float red[4096];       // 64x64 merge buffer (16 KB)

  f32x4 acc[8][2] = {};  // [a][half] : acc[a][0]=dv0..3, [1]=dv4..7
  const long nbase = (long)b * 4096 + chunk * 512 + wid * 128;
  const unsigned short* kp = kq + nbase * 512 + h * 64 + dk0;
  const unsigned short* vp = vq + nbase * 512 + h * 64 + dv0;

#pragma unroll 4
  for (int n = 0; n < 128; ++n) {
    u16x8 kk = *reinterpret_cast<const u16x8*>(kp + (long)n * 512);
    u16x8 vv = *reinterpret_cast<const u16x8*>(vp + (long)n * 512);
    float kf[8];
#pragma unroll
    for (int i = 0; i < 8; ++i) kf[i] = b2f(kk[i]);
    f32x4 v0 = {b2f(vv[0]), b2f(vv[1]), b2f(vv[2]), b2f(vv[3])};
    f32x4 v1 = {b2f(vv[4]), b2f(vv[5]), b2f(vv[6]), b2f(vv[7])};
#pragma unroll
    for (int a = 0; a < 8; ++a) {
      acc[a][0] += v0 * kf[a];
      acc[a][1] += v1 * kf[a];
    }
  }

  // merge the 4 waves' partial sums (sequential, deterministic order)
  if (wid == 0) {
#pragma unroll
    for (int a = 0; a < 8; ++a) {
      *reinterpret_cast<f32x4*>(&red[(dk0 + a) * 64 + dv0]) = acc[a][0];
      *reinterpret_cast<f32x4*>(&red[(dk0 + a) * 64 + dv0 + 4]) = acc[a][1];
    }
  }
  __syncthreads();
#pragma unroll 1
  for (int w = 1; w < 4; ++w) {
    if (wid == w) {
#pragma unroll
      for (int a = 0; a < 8; ++a) {
        f32x4* p0 = reinterpret_cast<f32x4*>(&red[(dk0 + a) * 64 + dv0]);
        f32x4* p1 = reinterpret_cast<f32x4*>(&red[(dk0 + a) * 64 + dv0 + 4]);
        *p0 += acc[a][0];
        *p1 += acc[a][1];
      }
    }
    __syncthreads();
  }

  float* pg = part + ((long)chunk * 64 + bh) * 4096;
#pragma unroll
  for (int i = 0; i < 4; ++i) {
    int e4 = i * 256 + tid;  // 1024 f32x4 chunks
    *reinterpret_cast<f32x4*>(pg + e4 * 4) =
        *reinterpret_cast<const f32x4*>(red + e4 * 4);
  }
}

// ---------------------------------------------------------------------------
// Merged: reduce partials + L2-norm (over dv) * gamma -> kvn in padded LDS,
// then Mt[b][c][h*64+dk] = sum_dv Wo[c][h*64+dv] * kvn[dk][dv] (4 waves = 4
// 128-col segs). kvn LDS pitch 72 shorts (144 B).
// ---------------------------------------------------------------------------
__global__ __launch_bounds__(256)
void kv_norm_mt(const float* __restrict__ part, const float* __restrict__ gamma,
                const unsigned short* __restrict__ Wo_b,
                unsigned short* __restrict__ Mt) {
  const int bh = blockIdx.x, h = bh & 7, b = bh >> 3;
  const int tid = threadIdx.x;
  __shared__ float kvs[4096];
  __shared__ float scale_s[64];
  __shared__ __align__(16) unsigned short kvn_l[64 * 72];  // padded

  // phase A: reduce 8 partial chunks
#pragma unroll
  for (int i = 0; i < 4; ++i) {
    int e4 = i * 256 + tid;
    const float* p = part + (long)bh * 4096 + e4 * 4;
    f32x4 s = {0.f, 0.f, 0.f, 0.f};
#pragma unroll
    for (int c = 0; c < NCHUNK; ++c) {
      f32x4 v = *reinterpret_cast<const f32x4*>(p + (long)c * 64 * 4096);
      s += v;
    }
    *reinterpret_cast<f32x4*>(kvs + e4 * 4) = s;
  }
  __syncthreads();
  if (tid < 64) {
    float s = 0.f;
    for (int dv = 0; dv < 64; ++dv) { float x = kvs[tid * 64 + dv]; s += x * x; }
    scale_s[tid] = gamma[h] / sqrtf(s);
  }
  __syncthreads();
#pragma unroll
  for (int i = 0; i < 4; ++i) {
    int e4 = i * 256 + tid;
    int row = e4 >> 4, c0 = (e4 & 15) * 4;
    float sc = scale_s[row];
    f32x4 v = *reinterpret_cast<const f32x4*>(kvs + e4 * 4);
    u16x4 o = {f2b(v[0] * sc), f2b(v[1] * sc), f2b(v[2] * sc), f2b(v[3] * sc)};
    *reinterpret_cast<u16x4*>(kvn_l + row * 72 + c0) = o;
  }
  __syncthreads();

  // phase B: mt for seg = wave id
  const int seg = tid >> 6;
  const int lane = tid & 63;
  const int r = lane & 15, g = lane >> 4;
  f32x4 acc[8][4] = {};
  s16x8 bf[2][4];
#pragma unroll
  for (int ks = 0; ks < 2; ++ks)
#pragma unroll
    for (int j = 0; j < 4; ++j)
      bf[ks][j] = *reinterpret_cast<const s16x8*>(
          kvn_l + (j * 16 + r) * 72 + ks * 32 + g * 8);
#pragma unroll
  for (int ks = 0; ks < 2; ++ks)
#pragma unroll
    for (int i = 0; i < 8; ++i) {
      s16x8 af = *reinterpret_cast<const s16x8*>(
          Wo_b + (long)(seg * 128 + i * 16 + r) * 512 + h * 64 + ks * 32 + g * 8);
#pragma unroll
      for (int j = 0; j < 4; ++j)
        acc[i][j] = __builtin_amdgcn_mfma_f32_16x16x32_bf16(af, bf[ks][j], acc[i][j], 0, 0, 0);
    }
#pragma unroll
  for (int i = 0; i < 8; ++i)
#pragma unroll
    for (int j = 0; j < 4; ++j)
#pragma unroll
      for (int ii = 0; ii < 4; ++ii) {
        int c = seg * 128 + i * 16 + g * 4 + ii;
        int dk = j * 16 + r;
        Mt[(long)b * 262144 + (long)c * 512 + h * 64 + dk] = f2b(acc[i][j][ii]);
      }
}

__global__ void cast4(const float* __restrict__ a0, const float* __restrict__ a1,
                      const float* __restrict__ a2, const float* __restrict__ a3,
                      unsigned short* __restrict__ o0, unsigned short* __restrict__ o1,
                      unsigned short* __restrict__ o2, unsigned short* __restrict__ o3) {
  const int y = blockIdx.y;
  const float* in = y == 0 ? a0 : (y == 1 ? a1 : (y == 2 ? a2 : a3));
  unsigned short* out = y == 0 ? o0 : (y == 1 ? o1 : (y == 2 ? o2 : o3));
  int i = blockIdx.x * 256 + threadIdx.x;
  f32x4 v = reinterpret_cast<const f32x4*>(in)[i];
  reinterpret_cast<u16x4*>(out)[i] = u16x4{f2b(v[0]), f2b(v[1]), f2b(v[2]), f2b(v[3])};
}

// ---------------------------------------------------------------------------
extern "C" void kernel_launch(void* const* d_in, const int* in_sizes, int n_in,
                              void* d_out, int out_size, void* d_ws, size_t ws_size,
                              hipStream_t stream) {
  const float* queries = (const float*)d_in[0];
  const float* keys    = (const float*)d_in[1];
  const float* values  = (const float*)d_in[2];
  const float* Wq = (const float*)d_in[3];
  const float* bq = (const float*)d_in[4];
  const float* Wk = (const float*)d_in[5];
  const float* bk = (const float*)d_in[6];
  const float* Wv = (const float*)d_in[7];
  const float* bv = (const float*)d_in[8];
  const float* Wo = (const float*)d_in[9];
  const float* bo = (const float*)d_in[10];
  const float* gamma = (const float*)d_in[11];

  unsigned short* Wq_b = (unsigned short*)d_ws;            // 512 KB each
  unsigned short* Wk_b = Wq_b + 262144;
  unsigned short* Wv_b = Wk_b + 262144;
  unsigned short* Wo_b = Wv_b + 262144;
  unsigned short* q_b  = Wo_b + 262144;                    // 32 MB (holds q_n)
  unsigned short* kvn  = q_b + 16777216;                   // 512 KB (unused)
  float* part = (float*)(kvn + 262144);                    // 8 MB
  unsigned short* Mt = (unsigned short*)(part + 2097152);  // 4 MB, after part
  unsigned short* k_b = (unsigned short*)d_out;            // d_out scratch
  unsigned short* v_b = k_b + 16777216;
  float* out = (float*)d_out;

  cast4<<<dim3(256, 4), 256, 0, stream>>>(Wq, Wk, Wv, Wo, Wq_b, Wk_b, Wv_b, Wo_b);

  proj_qkv<<<dim3(256, 3), 1024, 0, stream>>>(
      queries, keys, values, Wq_b, Wk_b, Wv_b, bq, bk, bv, q_b, k_b, v_b, gamma);

  kv_partial<<<dim3(NCHUNK, 64), 256, 0, stream>>>(k_b, v_b, part);
  kv_norm_mt<<<64, 256, 0, stream>>>(part, gamma, Wo_b, Mt);

  gemm_final<<<dim3(32, 8), 1024, 0, stream>>>(q_b, Mt, bo, out);
}